// Round 6
// baseline (126.420 us; speedup 1.0000x reference)
//
#include <hip/hip_runtime.h>
#include <stdint.h>

#define N_ 256
#define H_ 1024
#define BS_ 128

// ---------------- workspace layout (floats), all plain stores ----------------
// sk   : [128][1024]        @ 0          1 - tk^2
// oacc : [3][128][256]      @ 131072     reduced fo/go/ko
// opart: [32][3][128][256]  @ 229376     layer2 k-split partials (32 slices)
// jpart: [16][2][128][256]  @ 3375104    J h-split partials
#define WS_SK    0
#define WS_OACC  131072
#define WS_OPART 229376
#define WS_JPART 3375104
#define WS_FLOATS 4423680   // ~17.7 MB (harness ws is ~256 MB)

__device__ __forceinline__ float dot4(float4 a, float4 b) {
    return a.x * b.x + a.y * b.y + a.z * b.z + a.w * b.w;
}

// ---- K12U: R4's proven k12s with ONLY phase 1 re-laned. ----
// grid = 768 = 96 groups (m, ht 32-h slice) x 8 row-tiles (16 rows); 256 thr.
// LDS 50 KB -> 3 blocks/CU. Staging, phase 2, outputs: byte-identical to R4.
// Phase 1 change: thread = (h-pair, 4-row slot, kq k-interleave):
//   6 LDS reads per 8 dot4 (was 9); kq moved into LOW bank bits of the
//   k-chunk index -> X reads become 4 parallel broadcasts (was 4-way
//   same-quad collision); W reads uniform 8 lanes/group (b128 floor).
__global__ __launch_bounds__(256) void k12u(
    const float* __restrict__ x,
    const float* __restrict__ Wf1, const float* __restrict__ bf1,
    const float* __restrict__ Wg1, const float* __restrict__ bg1,
    const float* __restrict__ Wk1, const float* __restrict__ bk1,
    const float* __restrict__ Wf2, const float* __restrict__ bf2,
    const float* __restrict__ Wg2, const float* __restrict__ bg2,
    const float* __restrict__ Wk2, const float* __restrict__ bk2,
    float* __restrict__ sk, float* __restrict__ opart)
{
    const int bx  = blockIdx.x;
    const int sid = (bx & 7) * 96 + (bx >> 3);   // bijective XCD swizzle
    const int g   = sid >> 3;          // 0..95 weight group (m, ht)
    const int rt  = sid & 7;           // 0..7 row tile (16 rows)
    const int m   = g >> 5;            // 0..2
    const int ht  = g & 31;            // 0..31 h-slice of 32
    const int t   = threadIdx.x;
    const int h0  = ht * 32;
    const int r0  = rt * 16;

    const float* W1 = (m == 0) ? Wf1 : (m == 1) ? Wg1 : Wk1;
    const float* b1 = (m == 0) ? bf1 : (m == 1) ? bg1 : bk1;
    const float* W2 = (m == 0) ? Wf2 : (m == 1) ? Wg2 : Wk2;
    const float* b2 = (m == 0) ? bf2 : (m == 1) ? bg2 : bk2;

    __shared__ float4 wbuf[2048];                   // 32 KB, W1 then W2
    __shared__ __align__(16) float xs[16][256];     // 16 KB
    __shared__ __align__(16) float ts[16][32];      //  2 KB tanh acts

    // ---- stage x (16 rows) + W1 (32 rows), both flat coalesced (R4) ----
    {
        const float4* xsrc = (const float4*)(x + r0 * N_);
        #pragma unroll
        for (int v = 0; v < 4; ++v)
            ((float4*)xs)[t + 256 * v] = xsrc[t + 256 * v];
        const float4* wg = (const float4*)(W1 + h0 * N_);
        #pragma unroll
        for (int v = 0; v < 8; ++v) {
            const int f4  = t + 256 * v;            // 0..2047
            const int row = f4 >> 6, c = f4 & 63;
            wbuf[(row << 6) | (c & 48) | ((c & 15) ^ (row & 15))] = wg[f4];
        }
    }
    __syncthreads();

    // ---- phase 1 (re-laned): thread = (hp 2-h pair, kq, rq 4-row slot) ----
    {
        const int hp  = t & 15;          // h-pair: hloc = 2hp, 2hp+1
        const int kq  = (t >> 4) & 3;    // k interleave class (lane bits 4,5)
        const int rq  = t >> 6;          // 4-row slot (wave-uniform)
        const int h0l = hp * 2;

        float acc0[4] = {0.f, 0.f, 0.f, 0.f};   // hloc = 2hp
        float acc1[4] = {0.f, 0.f, 0.f, 0.f};   // hloc = 2hp+1
        #pragma unroll
        for (int cl = 0; cl < 16; ++cl) {
            const int kap = cl * 4 + kq;         // k-chunk; kq in low bank bits
            const int sw0 = (kap & 48) | ((kap & 15) ^ (h0l & 15));
            const int sw1 = (kap & 48) | ((kap & 15) ^ ((h0l + 1) & 15));
            const float4 w0 = wbuf[(h0l << 6) | sw0];
            const float4 w1 = wbuf[((h0l + 1) << 6) | sw1];
            #pragma unroll
            for (int rr = 0; rr < 4; ++rr) {
                const float4 xv = ((const float4*)xs[rq * 4 + rr])[kap];
                acc0[rr] += dot4(w0, xv);
                acc1[rr] += dot4(w1, xv);
            }
        }
        #pragma unroll
        for (int rr = 0; rr < 4; ++rr) {         // reduce over kq (bits 4,5)
            acc0[rr] += __shfl_xor(acc0[rr], 16, 64);
            acc0[rr] += __shfl_xor(acc0[rr], 32, 64);
            acc1[rr] += __shfl_xor(acc1[rr], 16, 64);
            acc1[rr] += __shfl_xor(acc1[rr], 32, 64);
        }
        // kq lane finalizes hh = kq>>1, rows rb=(kq&1)*2 + {0,1} (static sel)
        const int hh = kq >> 1;
        const int rb = (kq & 1) * 2;
        const float o0 = hh ? acc1[rb]     : acc0[rb];
        const float o1 = hh ? acc1[rb + 1] : acc0[rb + 1];
        const int hloc = h0l + hh;
        const int h    = h0 + hloc;
        const float bv = b1[h];
        const float v0 = tanhf(o0 + bv), v1 = tanhf(o1 + bv);
        const int rl = rq * 4 + rb;
        ts[rl][hloc]     = v0;
        ts[rl + 1][hloc] = v1;
        if (m == 2) {
            sk[(r0 + rl) * H_ + h]     = 1.0f - v0 * v0;
            sk[(r0 + rl + 1) * H_ + h] = 1.0f - v1 * v1;
        }
    }
    __syncthreads();

    // ---- re-stage wbuf with W2 slice [256 i][32 h] = 32 KB (R4) ----
    {
        #pragma unroll
        for (int v = 0; v < 8; ++v) {
            const int idx = t + 256 * v;            // 0..2047
            const int row = idx >> 3, c = idx & 7;  // 8 thr/row, 128B segments
            wbuf[(row << 3) | (c ^ (row & 7))] =
                ((const float4*)(W2 + row * H_ + h0))[c];
        }
    }
    __syncthreads();

    // ---- phase 2: thread = output channel i = t; 16 rows (R4, proven) ----
    {
        float acc[16];
        const float bv2 = (ht == 0) ? b2[t] : 0.0f;
        #pragma unroll
        for (int r = 0; r < 16; ++r) acc[r] = bv2;

        const float4* wrow = wbuf + (t << 3);
        #pragma unroll
        for (int c = 0; c < 8; ++c) {
            const float4 wv = wrow[c ^ (t & 7)];    // de-swizzle
            #pragma unroll
            for (int r = 0; r < 16; ++r) {
                const float4 av = ((const float4*)ts[r])[c];  // broadcast
                acc[r] += wv.x*av.x + wv.y*av.y + wv.z*av.z + wv.w*av.w;
            }
        }
        #pragma unroll
        for (int r = 0; r < 16; ++r)
            opart[((ht * 3 + m) * BS_ + r0 + r) * N_ + t] = acc[r];
    }
}

// ---- K25: reduce opart (32 slices) -> oacc. grid = 384 ----
__global__ __launch_bounds__(256) void k25_reduce(
    const float* __restrict__ opart, float* __restrict__ oacc)
{
    const int tid = blockIdx.x * 256 + threadIdx.x;   // 0..98303
    float s = 0.f;
    #pragma unroll
    for (int ks = 0; ks < 32; ++ks)
        s += opart[ks * (3 * BS_ * N_) + tid];
    oacc[tid] = s;
}

// ---- K3: fused v+J partials, reads reduced oacc. grid = 512 (proven) ----
__global__ __launch_bounds__(256) void k3_vj(
    const float* __restrict__ Wk1, const float* __restrict__ Wk2,
    const float* __restrict__ oacc, const float* __restrict__ sk,
    float* __restrict__ jpart)
{
    const int q  = blockIdx.x & 15;    // 0..15 h-slice
    const int rp = blockIdx.x >> 4;    // 0..31 row tile
    const int t  = threadIdx.x;
    const int r0 = rp * 4;
    const int h0 = q * 64;

    __shared__ float fos[4][256], gos[4][256];   // 8 KB
    __shared__ float sfv[4][64], sgv[4][64];     // 2 KB

    for (int u = t; u < 1024; u += 256) {
        const int r = u >> 8, i = u & 255;
        fos[r][i] = oacc[(r0 + r) * N_ + i];
        gos[r][i] = oacc[(BS_ + r0 + r) * N_ + i];
    }
    __syncthreads();

    {
        const int hl = t & 63;
        const int rl = t >> 6;         // 0..3, wave-uniform
        const int h  = h0 + hl;
        const float* w2 = Wk2 + h;
        float vf = 0.f, vg = 0.f;
        #pragma unroll 8
        for (int c = 0; c < 64; ++c) {
            const float4 of = ((const float4*)fos[rl])[c];
            const float4 og = ((const float4*)gos[rl])[c];
            const float w0  = w2[(4 * c + 0) * H_];
            const float w1v = w2[(4 * c + 1) * H_];
            const float w2v = w2[(4 * c + 2) * H_];
            const float w3  = w2[(4 * c + 3) * H_];
            vf += of.x * w0 + of.y * w1v + of.z * w2v + of.w * w3;
            vg += og.x * w0 + og.y * w1v + og.z * w2v + og.w * w3;
        }
        const float s = sk[(r0 + rl) * H_ + h];
        sfv[rl][hl] = s * vf;
        sgv[rl][hl] = s * vg;
    }
    __syncthreads();

    {
        float jf[4] = {0.f, 0.f, 0.f, 0.f};
        float jg[4] = {0.f, 0.f, 0.f, 0.f};
        const float* w1 = Wk1 + h0 * N_ + t;    // coalesced over t
        #pragma unroll 4
        for (int c = 0; c < 16; ++c) {
            const float w0  = w1[(4 * c + 0) * N_];
            const float wv1 = w1[(4 * c + 1) * N_];
            const float wv2 = w1[(4 * c + 2) * N_];
            const float wv3 = w1[(4 * c + 3) * N_];
            #pragma unroll
            for (int r = 0; r < 4; ++r) {
                const float4 sf = ((const float4*)sfv[r])[c];
                const float4 sg = ((const float4*)sgv[r])[c];
                jf[r] += sf.x * w0 + sf.y * wv1 + sf.z * wv2 + sf.w * wv3;
                jg[r] += sg.x * w0 + sg.y * wv1 + sg.z * wv2 + sg.w * wv3;
            }
        }
        #pragma unroll
        for (int r = 0; r < 4; ++r) {
            jpart[((q * 2 + 0) * BS_ + r0 + r) * N_ + t] = jf[r];
            jpart[((q * 2 + 1) * BS_ + r0 + r) * N_ + t] = jg[r];
        }
    }
}

// ---- K4: reduce jpart + norms + mask + output. grid = 128 (proven) ----
__global__ __launch_bounds__(256) void k4_final(
    const float* __restrict__ oacc,
    const float* __restrict__ jpart,
    float* __restrict__ out)
{
    const int r = blockIdx.x;
    const int t = threadIdx.x;
    __shared__ float red[12];

    const float fo = oacc[r * N_ + t];
    const float go = oacc[(BS_ + r) * N_ + t];
    const float ko = oacc[(2 * BS_ + r) * N_ + t];

    float jf = 0.f, jg = 0.f;
    #pragma unroll
    for (int q = 0; q < 16; ++q) {
        jf += jpart[((q * 2 + 0) * BS_ + r) * N_ + t];
        jg += jpart[((q * 2 + 1) * BS_ + r) * N_ + t];
    }

    float v0 = ko * ko, v1 = jf * jf, v2 = ko * jg;
    #pragma unroll
    for (int o = 32; o > 0; o >>= 1) {
        v0 += __shfl_xor(v0, o, 64);
        v1 += __shfl_xor(v1, o, 64);
        v2 += __shfl_xor(v2, o, 64);
    }
    const int wid = t >> 6;
    if ((t & 63) == 0) {
        red[wid * 3 + 0] = v0;
        red[wid * 3 + 1] = v1;
        red[wid * 3 + 2] = v2;
    }
    __syncthreads();
    const float kn2 = red[0] + red[3] + red[6] + red[9];
    const float jf2 = red[1] + red[4] + red[7] + red[10];
    const float kjg = red[2] + red[5] + red[8] + red[11];

    const float knorm = sqrtf(kn2);
    const float kn4 = kn2 * kn2;
    const float kn8 = kn4 * kn4;
    const float c1 = sqrtf(jf2) - 60.0f * kn8 * knorm;
    const float c2 = kjg - 20.0f * kn8 * kn2;
    const float scale = ((c1 > 1e-8f) || (c2 < -1e-8f)) ? 0.5f : 1.0f;

    out[r * N_ + t] = (fo + go) * scale;
}

// ================= fallback: round-2 proven fused kernel =================
__global__ __launch_bounds__(256) void manifold_fused(
    const float* __restrict__ x,
    const float* __restrict__ Wf1, const float* __restrict__ bf1v,
    const float* __restrict__ Wf2, const float* __restrict__ bf2v,
    const float* __restrict__ Wg1, const float* __restrict__ bg1v,
    const float* __restrict__ Wg2, const float* __restrict__ bg2v,
    const float* __restrict__ Wk1, const float* __restrict__ bk1v,
    const float* __restrict__ Wk2, const float* __restrict__ bk2v,
    float* __restrict__ out)
{
    const int b = blockIdx.x;
    const int t = threadIdx.x;
    __shared__ float xs[N_];
    __shared__ float tf[H_], tg[H_], tk[H_], sk[H_];
    __shared__ float fo[N_], go[N_];
    __shared__ float sfv[H_], sgv[H_];
    __shared__ float red[12];

    xs[t] = x[b * N_ + t];
    __syncthreads();
    {
        float acc[12];
        const float4* rows[12];
        #pragma unroll
        for (int m = 0; m < 4; ++m) {
            const int h = t + m * 256;
            rows[m]     = (const float4*)(Wf1 + h * N_);
            rows[4 + m] = (const float4*)(Wg1 + h * N_);
            rows[8 + m] = (const float4*)(Wk1 + h * N_);
            acc[m] = bf1v[h]; acc[4 + m] = bg1v[h]; acc[8 + m] = bk1v[h];
        }
        const float4* xs4 = (const float4*)xs;
        #pragma unroll 2
        for (int c = 0; c < 64; ++c) {
            float4 a = xs4[c];
            #pragma unroll
            for (int r = 0; r < 12; ++r) {
                float4 w = rows[r][c];
                acc[r] += w.x * a.x + w.y * a.y + w.z * a.z + w.w * a.w;
            }
        }
        #pragma unroll
        for (int m = 0; m < 4; ++m) {
            const int h = t + m * 256;
            float vtf = tanhf(acc[m]);
            float vtg = tanhf(acc[4 + m]);
            float vtk = tanhf(acc[8 + m]);
            tf[h] = vtf; tg[h] = vtg; tk[h] = vtk; sk[h] = 1.0f - vtk * vtk;
        }
    }
    __syncthreads();
    float af = bf2v[t], ag = bg2v[t], ak = bk2v[t];
    {
        const float4* rf = (const float4*)(Wf2 + t * H_);
        const float4* rg = (const float4*)(Wg2 + t * H_);
        const float4* rk = (const float4*)(Wk2 + t * H_);
        #pragma unroll 2
        for (int c = 0; c < 256; ++c) {
            float4 wf = rf[c], wg = rg[c], wk = rk[c];
            float4 vf = ((const float4*)tf)[c];
            af += wf.x*vf.x + wf.y*vf.y + wf.z*vf.z + wf.w*vf.w;
            float4 vg = ((const float4*)tg)[c];
            ag += wg.x*vg.x + wg.y*vg.y + wg.z*vg.z + wg.w*vg.w;
            float4 vk = ((const float4*)tk)[c];
            ak += wk.x*vk.x + wk.y*vk.y + wk.z*vk.z + wk.w*vk.w;
        }
    }
    fo[t] = af; go[t] = ag;
    __syncthreads();
    {
        float vf[4] = {0.f,0.f,0.f,0.f}, vg[4] = {0.f,0.f,0.f,0.f};
        const float* base = Wk2 + 4 * t;
        #pragma unroll 4
        for (int i = 0; i < N_; ++i) {
            float4 w = *(const float4*)(base + i * H_);
            float fv = fo[i], gv = go[i];
            vf[0]+=w.x*fv; vf[1]+=w.y*fv; vf[2]+=w.z*fv; vf[3]+=w.w*fv;
            vg[0]+=w.x*gv; vg[1]+=w.y*gv; vg[2]+=w.z*gv; vg[3]+=w.w*gv;
        }
        #pragma unroll
        for (int c = 0; c < 4; ++c) {
            sfv[4*t+c] = sk[4*t+c]*vf[c];
            sgv[4*t+c] = sk[4*t+c]*vg[c];
        }
    }
    __syncthreads();
    float jf = 0.f, jg = 0.f;
    {
        const float* col = Wk1 + t;
        #pragma unroll 4
        for (int c = 0; c < 256; ++c) {
            float4 s4 = ((const float4*)sfv)[c];
            float4 g4 = ((const float4*)sgv)[c];
            const int h = c * 4;
            float w0 = col[(h+0)*N_], w1 = col[(h+1)*N_];
            float w2 = col[(h+2)*N_], w3 = col[(h+3)*N_];
            jf += s4.x*w0 + s4.y*w1 + s4.z*w2 + s4.w*w3;
            jg += g4.x*w0 + g4.y*w1 + g4.z*w2 + g4.w*w3;
        }
    }
    float v0 = ak*ak, v1 = jf*jf, v2 = ak*jg;
    #pragma unroll
    for (int o = 32; o > 0; o >>= 1) {
        v0 += __shfl_xor(v0, o, 64);
        v1 += __shfl_xor(v1, o, 64);
        v2 += __shfl_xor(v2, o, 64);
    }
    const int wid = t >> 6;
    if ((t & 63) == 0) {
        red[wid*3+0] = v0; red[wid*3+1] = v1; red[wid*3+2] = v2;
    }
    __syncthreads();
    const float kn2 = red[0]+red[3]+red[6]+red[9];
    const float jf2 = red[1]+red[4]+red[7]+red[10];
    const float kjg = red[2]+red[5]+red[8]+red[11];
    const float knorm = sqrtf(kn2);
    const float kn4 = kn2*kn2, kn8 = kn4*kn4;
    const float c1 = sqrtf(jf2) - 60.0f*kn8*knorm;
    const float c2 = kjg - 20.0f*kn8*kn2;
    const float scale = ((c1 > 1e-8f) || (c2 < -1e-8f)) ? 0.5f : 1.0f;
    out[b*N_+t] = (af+ag)*scale;
}

extern "C" void kernel_launch(void* const* d_in, const int* in_sizes, int n_in,
                              void* d_out, int out_size, void* d_ws, size_t ws_size,
                              hipStream_t stream) {
    const float* x    = (const float*)d_in[1];
    const float* Wf1  = (const float*)d_in[2];
    const float* bf1v = (const float*)d_in[3];
    const float* Wf2  = (const float*)d_in[4];
    const float* bf2v = (const float*)d_in[5];
    const float* Wg1  = (const float*)d_in[6];
    const float* bg1v = (const float*)d_in[7];
    const float* Wg2  = (const float*)d_in[8];
    const float* bg2v = (const float*)d_in[9];
    const float* Wk1  = (const float*)d_in[10];
    const float* bk1v = (const float*)d_in[11];
    const float* Wk2  = (const float*)d_in[12];
    const float* bk2v = (const float*)d_in[13];
    float* out = (float*)d_out;

    if (ws_size < (size_t)WS_FLOATS * sizeof(float)) {
        manifold_fused<<<BS_, 256, 0, stream>>>(
            x, Wf1, bf1v, Wf2, bf2v, Wg1, bg1v, Wg2, bg2v,
            Wk1, bk1v, Wk2, bk2v, out);
        return;
    }

    float* ws    = (float*)d_ws;
    float* sk    = ws + WS_SK;
    float* oacc  = ws + WS_OACC;
    float* opart = ws + WS_OPART;
    float* jpart = ws + WS_JPART;

    k12u      <<<768, 256, 0, stream>>>(x, Wf1, bf1v, Wg1, bg1v, Wk1, bk1v,
                                        Wf2, bf2v, Wg2, bg2v, Wk2, bk2v,
                                        sk, opart);
    k25_reduce<<<384, 256, 0, stream>>>(opart, oacc);
    k3_vj     <<<512, 256, 0, stream>>>(Wk1, Wk2, oacc, sk, jpart);
    k4_final  <<<BS_, 256, 0, stream>>>(oacc, jpart, out);
}

// Round 7
// 114.801 us; speedup vs baseline: 1.1012x; 1.1012x over previous
//
#include <hip/hip_runtime.h>
#include <stdint.h>

#define N_ 256
#define H_ 1024
#define BS_ 128

// ---------------- workspace layout (floats) ----------------
// sk   : [128][1024]          @ 0         1 - tk^2
// oacc : [3][128][256]        @ 131072    reduced fo/go/ko
// opart: [16][3][128][256]    @ 229376    layer2 k-split partials (16 slices)
// jpart: [16][2][128][256]    @ 1802240   J h-split partials
// frag arrays (bf16 hi/lo, MFMA-fragment-ordered, written by kprep):
// xh/xl  : 64 tiles  x 64 lanes x 8 bf16   @ 2850816 / 2867200
// w1h/w1l: 3m x 512 tiles x 64 x 8         @ 2883584 / 3276800
// w2h/w2l: 3m x 512 tiles x 64 x 8         @ 3670016 / 4063232
#define WS_SK    0
#define WS_OACC  131072
#define WS_OPART 229376
#define WS_JPART 1802240
#define WS_XH    2850816
#define WS_XL    2867200
#define WS_W1H   2883584
#define WS_W1L   3276800
#define WS_W2H   3670016
#define WS_W2L   4063232
#define WS_FLOATS 4456448   // ~17.8 MB (harness ws is ~256 MB)

typedef __attribute__((ext_vector_type(8))) short short8v;  // 8 bf16 = 4 VGPR
typedef __attribute__((ext_vector_type(4))) float f32x4;

__device__ __forceinline__ ushort bhi(float v) {
    return (ushort)(__float_as_uint(v) >> 16);          // truncate to bf16
}
__device__ __forceinline__ float btrunc(float v) {
    return __uint_as_float(__float_as_uint(v) & 0xFFFF0000u);
}

// ---- KPREP: fp32 -> split-bf16 (hi + lo), written in MFMA FRAGMENT ORDER ----
// frag for tile T: lane l holds src[row = T.n*16 + (l&15)][k = T.k*32 + (l>>4)*8 + i]
// stored at base + (T*64 + l)*8 bf16 -> GEMM frag load = one coalesced b128.
// tiles: X 64 (rt*8+ks) | W1 3x512 (ht*8+ks) | W2 3x512 (it*32+hk). grid 784x256.
__global__ __launch_bounds__(256) void kprep(
    const float* __restrict__ x,
    const float* __restrict__ Wf1, const float* __restrict__ Wg1,
    const float* __restrict__ Wk1,
    const float* __restrict__ Wf2, const float* __restrict__ Wg2,
    const float* __restrict__ Wk2,
    ushort* __restrict__ xh, ushort* __restrict__ xl,
    ushort* __restrict__ w1h, ushort* __restrict__ w1l,
    ushort* __restrict__ w2h, ushort* __restrict__ w2l)
{
    const int T = blockIdx.x * 4 + (threadIdx.x >> 6);   // 0..3135
    const int l = threadIdx.x & 63;
    const int c16 = l & 15, g = l >> 4;

    const float* src;
    ushort *ph, *pl;
    int dst;
    if (T < 64) {                                        // X tiles
        const int rt = T >> 3, ks = T & 7;
        src = x + (rt * 16 + c16) * N_ + ks * 32 + g * 8;
        dst = (T * 64 + l) * 8;
        ph = xh; pl = xl;
    } else if (T < 64 + 1536) {                          // W1 tiles
        const int T2 = T - 64;
        const int m = T2 >> 9, rem = T2 & 511;           // rem = ht*8 + ks
        const int htg = rem >> 3, ks = rem & 7;
        const float* W1 = (m == 0) ? Wf1 : (m == 1) ? Wg1 : Wk1;
        src = W1 + (htg * 16 + c16) * N_ + ks * 32 + g * 8;
        dst = ((m << 15) + rem * 64 + l) * 8;
        ph = w1h; pl = w1l;
    } else {                                             // W2 tiles
        const int T3 = T - 64 - 1536;
        const int m = T3 >> 9, rem = T3 & 511;           // rem = it*32 + hk
        const int it = rem >> 5, hk = rem & 31;
        const float* W2 = (m == 0) ? Wf2 : (m == 1) ? Wg2 : Wk2;
        src = W2 + (it * 16 + c16) * H_ + hk * 32 + g * 8;
        dst = ((m << 15) + rem * 64 + l) * 8;
        ph = w2h; pl = w2l;
    }
    const float4 a = *(const float4*)src;
    const float4 b = *(const float4*)(src + 4);
    const float s[8] = {a.x, a.y, a.z, a.w, b.x, b.y, b.z, b.w};
    union { short8v v; ushort u[8]; } H, L;
    #pragma unroll
    for (int i = 0; i < 8; ++i) {
        H.u[i] = bhi(s[i]);
        L.u[i] = bhi(s[i] - btrunc(s[i]));
    }
    *(short8v*)(ph + dst) = H.v;
    *(short8v*)(pl + dst) = L.v;
}

// ---- K12M: layer1+layer2 via split-bf16 MFMA (D=A*B+C, 16x16x32). ----
// grid = 384 = 3m x 16 hs(64-h slice) x 8 rt(16 rows); 256 thr = 4 waves.
// Wave w: layer1 h-tile hs*4+w; layer2 i-range w*64..w*64+63 (4 i-tiles).
// Frag layout (m89/§5-template): A row=l&15, B col=l&15, k=(l>>4)*8+i;
// D col=l&15, row=(l>>4)*4+reg. Only LDS: 4 KB swizzled tanh hi/lo (ts).
// err ~2^-16 rel (drop lo*lo); mask margins ~1e12 -> no flip risk.
__global__ __launch_bounds__(256) void k12m(
    const ushort* __restrict__ xh, const ushort* __restrict__ xl,
    const ushort* __restrict__ w1h, const ushort* __restrict__ w1l,
    const ushort* __restrict__ w2h, const ushort* __restrict__ w2l,
    const float* __restrict__ bf1, const float* __restrict__ bg1,
    const float* __restrict__ bk1,
    const float* __restrict__ bf2, const float* __restrict__ bg2,
    const float* __restrict__ bk2,
    float* __restrict__ sk, float* __restrict__ opart)
{
    const int bx  = blockIdx.x;
    const int sid = (bx & 7) * 48 + (bx >> 3);   // bijective XCD swizzle
    const int m   = sid >> 7;          // 0..2
    const int rem = sid & 127;
    const int hs  = rem >> 3;          // 0..15  64-h slice (= opart k-slice)
    const int rt  = rem & 7;           // 0..7   16-row tile
    const int t = threadIdx.x, w = t >> 6, l = t & 63;
    const int col = l & 15, g = l >> 4;
    const int r0 = rt * 16;

    const float* b1 = (m == 0) ? bf1 : (m == 1) ? bg1 : bk1;
    const float* b2 = (m == 0) ? bf2 : (m == 1) ? bg2 : bk2;

    const short8v* XH  = (const short8v*)xh;
    const short8v* XL  = (const short8v*)xl;
    const short8v* W1H = (const short8v*)w1h + m * 32768;
    const short8v* W1L = (const short8v*)w1l + m * 32768;
    const short8v* W2H = (const short8v*)w2h + m * 32768;
    const short8v* W2L = (const short8v*)w2l + m * 32768;

    __shared__ __align__(16) ushort tsh[1024], tsl[1024];  // [16r][8 chunk][8]

    // ---- layer 1: D[16r x 16h] over K=256 (8 ksteps x 3 split-MFMA) ----
    const int htile = hs * 4 + w;      // 0..63
    f32x4 acc1 = {0.f, 0.f, 0.f, 0.f};
    #pragma unroll
    for (int ks = 0; ks < 8; ++ks) {
        const short8v axh = XH[(rt * 8 + ks) * 64 + l];
        const short8v axl = XL[(rt * 8 + ks) * 64 + l];
        const short8v bh  = W1H[(htile * 8 + ks) * 64 + l];
        const short8v bl  = W1L[(htile * 8 + ks) * 64 + l];
        acc1 = __builtin_amdgcn_mfma_f32_16x16x32_bf16(axl, bh, acc1, 0, 0, 0);
        acc1 = __builtin_amdgcn_mfma_f32_16x16x32_bf16(axh, bl, acc1, 0, 0, 0);
        acc1 = __builtin_amdgcn_mfma_f32_16x16x32_bf16(axh, bh, acc1, 0, 0, 0);
    }
    {
        const int h  = htile * 16 + col;
        const float bv = b1[h];
        const int hl_ = w * 16 + col;            // h within 64-slice
        const int cb = hl_ >> 3, wi = hl_ & 7;   // chunk, within-chunk
        #pragma unroll
        for (int j = 0; j < 4; ++j) {
            const int row = g * 4 + j;
            const float v = tanhf(acc1[j] + bv);
            if (m == 2) sk[(r0 + row) * H_ + h] = 1.0f - v * v;
            const int cs = cb ^ (row & 7);       // XOR-swizzle (T2)
            tsh[row * 64 + cs * 8 + wi] = bhi(v);
            tsl[row * 64 + cs * 8 + wi] = bhi(v - btrunc(v));
        }
    }
    __syncthreads();

    // ---- layer 2: D[16r x 64i] partial over this 64-h slice (2 ksteps) ----
    f32x4 acc2[4] = {{0.f,0.f,0.f,0.f}, {0.f,0.f,0.f,0.f},
                     {0.f,0.f,0.f,0.f}, {0.f,0.f,0.f,0.f}};
    #pragma unroll
    for (int ks2 = 0; ks2 < 2; ++ks2) {
        const int cs = (ks2 * 4 + g) ^ (col & 7);       // A row = col
        const short8v ath = *(const short8v*)&tsh[col * 64 + cs * 8];
        const short8v atl = *(const short8v*)&tsl[col * 64 + cs * 8];
        const int hk = hs * 2 + ks2;                    // global 32-h kstep
        #pragma unroll
        for (int n = 0; n < 4; ++n) {
            const int itg = w * 4 + n;                  // i-tile 0..15
            const short8v bh = W2H[(itg * 32 + hk) * 64 + l];
            const short8v bl = W2L[(itg * 32 + hk) * 64 + l];
            acc2[n] = __builtin_amdgcn_mfma_f32_16x16x32_bf16(atl, bh, acc2[n], 0, 0, 0);
            acc2[n] = __builtin_amdgcn_mfma_f32_16x16x32_bf16(ath, bl, acc2[n], 0, 0, 0);
            acc2[n] = __builtin_amdgcn_mfma_f32_16x16x32_bf16(ath, bh, acc2[n], 0, 0, 0);
        }
    }
    #pragma unroll
    for (int n = 0; n < 4; ++n) {
        const int i = (w * 4 + n) * 16 + col;
        const float bias = (hs == 0) ? b2[i] : 0.0f;
        #pragma unroll
        for (int j = 0; j < 4; ++j) {
            const int row = g * 4 + j;
            opart[((hs * 3 + m) * BS_ + r0 + row) * N_ + i] = acc2[n][j] + bias;
        }
    }
}

// ---- K25: reduce opart (16 slices) -> oacc. grid = 384 ----
__global__ __launch_bounds__(256) void k25_reduce(
    const float* __restrict__ opart, float* __restrict__ oacc)
{
    const int tid = blockIdx.x * 256 + threadIdx.x;   // 0..98303
    float s = 0.f;
    #pragma unroll
    for (int ks = 0; ks < 16; ++ks)
        s += opart[ks * (3 * BS_ * N_) + tid];
    oacc[tid] = s;
}

// ---- K3: fused v+J partials, reads reduced oacc. grid = 512 (proven) ----
__global__ __launch_bounds__(256) void k3_vj(
    const float* __restrict__ Wk1, const float* __restrict__ Wk2,
    const float* __restrict__ oacc, const float* __restrict__ sk,
    float* __restrict__ jpart)
{
    const int q  = blockIdx.x & 15;    // 0..15 h-slice
    const int rp = blockIdx.x >> 4;    // 0..31 row tile
    const int t  = threadIdx.x;
    const int r0 = rp * 4;
    const int h0 = q * 64;

    __shared__ float fos[4][256], gos[4][256];   // 8 KB
    __shared__ float sfv[4][64], sgv[4][64];     // 2 KB

    for (int u = t; u < 1024; u += 256) {
        const int r = u >> 8, i = u & 255;
        fos[r][i] = oacc[(r0 + r) * N_ + i];
        gos[r][i] = oacc[(BS_ + r0 + r) * N_ + i];
    }
    __syncthreads();

    {
        const int hl = t & 63;
        const int rl = t >> 6;         // 0..3, wave-uniform
        const int h  = h0 + hl;
        const float* w2 = Wk2 + h;
        float vf = 0.f, vg = 0.f;
        #pragma unroll 8
        for (int c = 0; c < 64; ++c) {
            const float4 of = ((const float4*)fos[rl])[c];
            const float4 og = ((const float4*)gos[rl])[c];
            const float w0  = w2[(4 * c + 0) * H_];
            const float w1v = w2[(4 * c + 1) * H_];
            const float w2v = w2[(4 * c + 2) * H_];
            const float w3  = w2[(4 * c + 3) * H_];
            vf += of.x * w0 + of.y * w1v + of.z * w2v + of.w * w3;
            vg += og.x * w0 + og.y * w1v + og.z * w2v + og.w * w3;
        }
        const float s = sk[(r0 + rl) * H_ + h];
        sfv[rl][hl] = s * vf;
        sgv[rl][hl] = s * vg;
    }
    __syncthreads();

    {
        float jf[4] = {0.f, 0.f, 0.f, 0.f};
        float jg[4] = {0.f, 0.f, 0.f, 0.f};
        const float* w1 = Wk1 + h0 * N_ + t;    // coalesced over t
        #pragma unroll 4
        for (int c = 0; c < 16; ++c) {
            const float w0  = w1[(4 * c + 0) * N_];
            const float wv1 = w1[(4 * c + 1) * N_];
            const float wv2 = w1[(4 * c + 2) * N_];
            const float wv3 = w1[(4 * c + 3) * N_];
            #pragma unroll
            for (int r = 0; r < 4; ++r) {
                const float4 sf = ((const float4*)sfv[r])[c];
                const float4 sg = ((const float4*)sgv[r])[c];
                jf[r] += sf.x * w0 + sf.y * wv1 + sf.z * wv2 + sf.w * wv3;
                jg[r] += sg.x * w0 + sg.y * wv1 + sg.z * wv2 + sg.w * wv3;
            }
        }
        #pragma unroll
        for (int r = 0; r < 4; ++r) {
            jpart[((q * 2 + 0) * BS_ + r0 + r) * N_ + t] = jf[r];
            jpart[((q * 2 + 1) * BS_ + r0 + r) * N_ + t] = jg[r];
        }
    }
}

// ---- K4: reduce jpart + norms + mask + output. grid = 128 (proven) ----
__global__ __launch_bounds__(256) void k4_final(
    const float* __restrict__ oacc,
    const float* __restrict__ jpart,
    float* __restrict__ out)
{
    const int r = blockIdx.x;
    const int t = threadIdx.x;
    __shared__ float red[12];

    const float fo = oacc[r * N_ + t];
    const float go = oacc[(BS_ + r) * N_ + t];
    const float ko = oacc[(2 * BS_ + r) * N_ + t];

    float jf = 0.f, jg = 0.f;
    #pragma unroll
    for (int q = 0; q < 16; ++q) {
        jf += jpart[((q * 2 + 0) * BS_ + r) * N_ + t];
        jg += jpart[((q * 2 + 1) * BS_ + r) * N_ + t];
    }

    float v0 = ko * ko, v1 = jf * jf, v2 = ko * jg;
    #pragma unroll
    for (int o = 32; o > 0; o >>= 1) {
        v0 += __shfl_xor(v0, o, 64);
        v1 += __shfl_xor(v1, o, 64);
        v2 += __shfl_xor(v2, o, 64);
    }
    const int wid = t >> 6;
    if ((t & 63) == 0) {
        red[wid * 3 + 0] = v0;
        red[wid * 3 + 1] = v1;
        red[wid * 3 + 2] = v2;
    }
    __syncthreads();
    const float kn2 = red[0] + red[3] + red[6] + red[9];
    const float jf2 = red[1] + red[4] + red[7] + red[10];
    const float kjg = red[2] + red[5] + red[8] + red[11];

    const float knorm = sqrtf(kn2);
    const float kn4 = kn2 * kn2;
    const float kn8 = kn4 * kn4;
    const float c1 = sqrtf(jf2) - 60.0f * kn8 * knorm;
    const float c2 = kjg - 20.0f * kn8 * kn2;
    const float scale = ((c1 > 1e-8f) || (c2 < -1e-8f)) ? 0.5f : 1.0f;

    out[r * N_ + t] = (fo + go) * scale;
}

// ================= fallback: round-2 proven fused kernel =================
__global__ __launch_bounds__(256) void manifold_fused(
    const float* __restrict__ x,
    const float* __restrict__ Wf1, const float* __restrict__ bf1v,
    const float* __restrict__ Wf2, const float* __restrict__ bf2v,
    const float* __restrict__ Wg1, const float* __restrict__ bg1v,
    const float* __restrict__ Wg2, const float* __restrict__ bg2v,
    const float* __restrict__ Wk1, const float* __restrict__ bk1v,
    const float* __restrict__ Wk2, const float* __restrict__ bk2v,
    float* __restrict__ out)
{
    const int b = blockIdx.x;
    const int t = threadIdx.x;
    __shared__ float xs[N_];
    __shared__ float tf[H_], tg[H_], tk[H_], sk[H_];
    __shared__ float fo[N_], go[N_];
    __shared__ float sfv[H_], sgv[H_];
    __shared__ float red[12];

    xs[t] = x[b * N_ + t];
    __syncthreads();
    {
        float acc[12];
        const float4* rows[12];
        #pragma unroll
        for (int m = 0; m < 4; ++m) {
            const int h = t + m * 256;
            rows[m]     = (const float4*)(Wf1 + h * N_);
            rows[4 + m] = (const float4*)(Wg1 + h * N_);
            rows[8 + m] = (const float4*)(Wk1 + h * N_);
            acc[m] = bf1v[h]; acc[4 + m] = bg1v[h]; acc[8 + m] = bk1v[h];
        }
        const float4* xs4 = (const float4*)xs;
        #pragma unroll 2
        for (int c = 0; c < 64; ++c) {
            float4 a = xs4[c];
            #pragma unroll
            for (int r = 0; r < 12; ++r) {
                float4 w = rows[r][c];
                acc[r] += w.x * a.x + w.y * a.y + w.z * a.z + w.w * a.w;
            }
        }
        #pragma unroll
        for (int m = 0; m < 4; ++m) {
            const int h = t + m * 256;
            float vtf = tanhf(acc[m]);
            float vtg = tanhf(acc[4 + m]);
            float vtk = tanhf(acc[8 + m]);
            tf[h] = vtf; tg[h] = vtg; tk[h] = vtk; sk[h] = 1.0f - vtk * vtk;
        }
    }
    __syncthreads();
    float af = bf2v[t], ag = bg2v[t], ak = bk2v[t];
    {
        const float4* rf = (const float4*)(Wf2 + t * H_);
        const float4* rg = (const float4*)(Wg2 + t * H_);
        const float4* rk = (const float4*)(Wk2 + t * H_);
        #pragma unroll 2
        for (int c = 0; c < 256; ++c) {
            float4 wf = rf[c], wg = rg[c], wk = rk[c];
            float4 vf = ((const float4*)tf)[c];
            af += wf.x*vf.x + wf.y*vf.y + wf.z*vf.z + wf.w*vf.w;
            float4 vg = ((const float4*)tg)[c];
            ag += wg.x*vg.x + wg.y*vg.y + wg.z*vg.z + wg.w*vg.w;
            float4 vk = ((const float4*)tk)[c];
            ak += wk.x*vk.x + wk.y*vk.y + wk.z*vk.z + wk.w*vk.w;
        }
    }
    fo[t] = af; go[t] = ag;
    __syncthreads();
    {
        float vf[4] = {0.f,0.f,0.f,0.f}, vg[4] = {0.f,0.f,0.f,0.f};
        const float* base = Wk2 + 4 * t;
        #pragma unroll 4
        for (int i = 0; i < N_; ++i) {
            float4 w = *(const float4*)(base + i * H_);
            float fv = fo[i], gv = go[i];
            vf[0]+=w.x*fv; vf[1]+=w.y*fv; vf[2]+=w.z*fv; vf[3]+=w.w*fv;
            vg[0]+=w.x*gv; vg[1]+=w.y*gv; vg[2]+=w.z*gv; vg[3]+=w.w*gv;
        }
        #pragma unroll
        for (int c = 0; c < 4; ++c) {
            sfv[4*t+c] = sk[4*t+c]*vf[c];
            sgv[4*t+c] = sk[4*t+c]*vg[c];
        }
    }
    __syncthreads();
    float jf = 0.f, jg = 0.f;
    {
        const float* col = Wk1 + t;
        #pragma unroll 4
        for (int c = 0; c < 256; ++c) {
            float4 s4 = ((const float4*)sfv)[c];
            float4 g4 = ((const float4*)sgv)[c];
            const int h = c * 4;
            float w0 = col[(h+0)*N_], w1 = col[(h+1)*N_];
            float w2 = col[(h+2)*N_], w3 = col[(h+3)*N_];
            jf += s4.x*w0 + s4.y*w1 + s4.z*w2 + s4.w*w3;
            jg += g4.x*w0 + g4.y*w1 + g4.z*w2 + g4.w*w3;
        }
    }
    float v0 = ak*ak, v1 = jf*jf, v2 = ak*jg;
    #pragma unroll
    for (int o = 32; o > 0; o >>= 1) {
        v0 += __shfl_xor(v0, o, 64);
        v1 += __shfl_xor(v1, o, 64);
        v2 += __shfl_xor(v2, o, 64);
    }
    const int wid = t >> 6;
    if ((t & 63) == 0) {
        red[wid*3+0] = v0; red[wid*3+1] = v1; red[wid*3+2] = v2;
    }
    __syncthreads();
    const float kn2 = red[0]+red[3]+red[6]+red[9];
    const float jf2 = red[1]+red[4]+red[7]+red[10];
    const float kjg = red[2]+red[5]+red[8]+red[11];
    const float knorm = sqrtf(kn2);
    const float kn4 = kn2*kn2, kn8 = kn4*kn4;
    const float c1 = sqrtf(jf2) - 60.0f*kn8*knorm;
    const float c2 = kjg - 20.0f*kn8*kn2;
    const float scale = ((c1 > 1e-8f) || (c2 < -1e-8f)) ? 0.5f : 1.0f;
    out[b*N_+t] = (af+ag)*scale;
}

extern "C" void kernel_launch(void* const* d_in, const int* in_sizes, int n_in,
                              void* d_out, int out_size, void* d_ws, size_t ws_size,
                              hipStream_t stream) {
    const float* x    = (const float*)d_in[1];
    const float* Wf1  = (const float*)d_in[2];
    const float* bf1v = (const float*)d_in[3];
    const float* Wf2  = (const float*)d_in[4];
    const float* bf2v = (const float*)d_in[5];
    const float* Wg1  = (const float*)d_in[6];
    const float* bg1v = (const float*)d_in[7];
    const float* Wg2  = (const float*)d_in[8];
    const float* bg2v = (const float*)d_in[9];
    const float* Wk1  = (const float*)d_in[10];
    const float* bk1v = (const float*)d_in[11];
    const float* Wk2  = (const float*)d_in[12];
    const float* bk2v = (const float*)d_in[13];
    float* out = (float*)d_out;

    if (ws_size < (size_t)WS_FLOATS * sizeof(float)) {
        manifold_fused<<<BS_, 256, 0, stream>>>(
            x, Wf1, bf1v, Wf2, bf2v, Wg1, bg1v, Wg2, bg2v,
            Wk1, bk1v, Wk2, bk2v, out);
        return;
    }

    float* ws    = (float*)d_ws;
    float* sk    = ws + WS_SK;
    float* oacc  = ws + WS_OACC;
    float* opart = ws + WS_OPART;
    float* jpart = ws + WS_JPART;
    ushort* xh  = (ushort*)(ws + WS_XH);
    ushort* xl  = (ushort*)(ws + WS_XL);
    ushort* w1h = (ushort*)(ws + WS_W1H);
    ushort* w1l = (ushort*)(ws + WS_W1L);
    ushort* w2h = (ushort*)(ws + WS_W2H);
    ushort* w2l = (ushort*)(ws + WS_W2L);

    kprep     <<<784, 256, 0, stream>>>(x, Wf1, Wg1, Wk1, Wf2, Wg2, Wk2,
                                        xh, xl, w1h, w1l, w2h, w2l);
    k12m      <<<384, 256, 0, stream>>>(xh, xl, w1h, w1l, w2h, w2l,
                                        bf1v, bg1v, bk1v, bf2v, bg2v, bk2v,
                                        sk, opart);
    k25_reduce<<<384, 256, 0, stream>>>(opart, oacc);
    k3_vj     <<<512, 256, 0, stream>>>(Wk1, Wk2, oacc, sk, jpart);
    k4_final  <<<BS_, 256, 0, stream>>>(oacc, jpart, out);
}